// Round 6
// baseline (1072.241 us; speedup 1.0000x reference)
//
#include <hip/hip_runtime.h>
#include <math.h>

// BiometricLSTM: 2-layer LSTM, B=512, T=2048, I=3, H=64, fp32 in/out. Output = final h2 (B,64).
//
// R23: R20 (best, 1064.1 us) + three chain micro-cuts. Structure unchanged.
//  (a) Split z-chained gate MFMA pairs (L0 and L1): acc0=mfma(a0,w0,cbias),
//      acc1=mfma(a1,w1,0) complete in PARALLEL; merge with scalar
//      sel4(acc0)+sel4(acc1) (1 extra add on chain vs a full 2nd MFMA dep
//      latency, ~15cy). R18's failed version bundled this with the 48-FMA
//      C-init fold + f32x4 merges; this is the clean scalar form.
//      pI (off-critical, deadline next iter) stays z-chained.
//  (b) log2e prescale: gate rows of ALL weights/biases/x-weights scaled by
//      log2e (i,f,o) or 2*log2e (g) at load time. Activations then use bare
//      v_exp_f32 (exp2): sigmoid(x)=rcp(1+exp2(-y)), tanh-gate=1-2*rcp(exp2(y)+1),
//      tanh(cst)= 1 mul + exp2 (was 2 muls). Exact rescale; removes ~5 muls/step,
//      2 on the c-recurrence. f16 weight range 0.125->0.36, safe.
//  (c) s_setprio(1) on L0 waves: each SIMD hosts 1 L0 (16 MFMA, critical pole) +
//      1 L1 (8 MFMA, lag-2 slack) wave; bias contended issue slots to the pole.
// All else R20 verbatim: 128 blocks x 512 thr, split waves, gates-before-pI,
// unroll-2 (compile-time parity), M=4 replicated rows, quad-selected update,
// HSTR=80, x-proj hoisted pre-MFMA, hoisted pIbuf reads, ONE barrier/iter,
// f16 weights/h + f32 accum.
// Parities: h1[t]@t&1; h2[t]@t&1; pIbuf write@prev / read@cur disjoint.

typedef _Float16 half8 __attribute__((ext_vector_type(8)));
typedef float    f32x4 __attribute__((ext_vector_type(4)));

constexpr int TT = 2048;
constexpr int HSTR = 80;   // h row stride in halves (160 B)

#define LOG2E  1.44269504088896340736f
#define LOG2E2 2.88539008177792681472f

// y = x*log2e already applied upstream: sigmoid(x) = 1/(1+2^-y)
__device__ __forceinline__ float sig_p(float y) {
    return __builtin_amdgcn_rcpf(1.0f + __builtin_amdgcn_exp2f(-y));
}
// y = x*2log2e already applied upstream: tanh(x) = 1 - 2/(2^y + 1)
__device__ __forceinline__ float tanh_p(float y) {
    return 1.0f - 2.0f * __builtin_amdgcn_rcpf(__builtin_amdgcn_exp2f(y) + 1.0f);
}
// select component q (lane's quad) from an f32x4 accumulator
__device__ __forceinline__ float sel4(f32x4 v, int q) {
    float r = v[0];
    r = (q == 1) ? v[1] : r;
    r = (q == 2) ? v[2] : r;
    r = (q == 3) ? v[3] : r;
    return r;
}

__global__ __launch_bounds__(512) void lstm2_fused(
    const float* __restrict__ x,
    const float* __restrict__ Wih0, const float* __restrict__ Whh0,
    const float* __restrict__ bih0, const float* __restrict__ bhh0,
    const float* __restrict__ Wih1, const float* __restrict__ Whh1,
    const float* __restrict__ bih1, const float* __restrict__ bhh1,
    float* __restrict__ out)
{
    __shared__ __align__(16) _Float16 h1a[2][4 * HSTR];   // [parity][seq*HSTR + elem]
    __shared__ __align__(16) _Float16 h2a[2][4 * HSTR];
    __shared__ __align__(16) float4   pIbuf[2][4][64];    // [stepParity][class][col] = 4 seqs

    const int tid  = threadIdx.x;
    const int lane = tid & 63;
    const int wid  = tid >> 6;
    const int quad = lane >> 4;
    const int l16  = lane & 15;
    const bool isL1 = (wid >= 4);
    const int col  = (wid & 3) * 16 + l16;   // gate-elem column this lane owns per class

    // ---- zero h double-buffers ----
    for (int i = tid; i < 2 * 4 * HSTR; i += 512) {
        ((_Float16*)h1a)[i] = (_Float16)0.0f;
        ((_Float16*)h2a)[i] = (_Float16)0.0f;
    }

    // ---- weights (B-frags, f16), log2e-prescaled per gate class ----
    // class c: 0=i 1=f 2=g 3=o; scale = log2e (sigmoid) or 2*log2e (tanh g)
    half8 wA[4][2];      // L0 waves: Whh0 | L1 waves: Whh1
    half8 wB[4][2];      // L0 waves only: Wih1
    f32x4 cbias[4];      // bias splat (prescaled), MFMA C-init
    float wxa[4], wxb[4], wxc[4];            // L0 only (prescaled)
    #pragma unroll
    for (int c = 0; c < 4; ++c) {
        const int row = c * 64 + col;
        const float sc = (c == 2) ? LOG2E2 : LOG2E;
        if (!isL1) {
            #pragma unroll
            for (int f = 0; f < 2; ++f) {
                const float* p = Whh0 + (size_t)row * 64 + f * 32 + quad * 8;
                half8 h;
                #pragma unroll
                for (int u = 0; u < 8; ++u) h[u] = (_Float16)(p[u] * sc);
                wA[c][f] = h;
                const float* q = Wih1 + (size_t)row * 64 + f * 32 + quad * 8;
                half8 g;
                #pragma unroll
                for (int u = 0; u < 8; ++u) g[u] = (_Float16)(q[u] * sc);
                wB[c][f] = g;
            }
            const float b = (bih0[row] + bhh0[row]) * sc;
            cbias[c] = f32x4{b, b, b, b};
            wxa[c] = Wih0[row*3+0] * sc;
            wxb[c] = Wih0[row*3+1] * sc;
            wxc[c] = Wih0[row*3+2] * sc;
        } else {
            #pragma unroll
            for (int f = 0; f < 2; ++f) {
                const float* p = Whh1 + (size_t)row * 64 + f * 32 + quad * 8;
                half8 h;
                #pragma unroll
                for (int u = 0; u < 8; ++u) h[u] = (_Float16)(p[u] * sc);
                wA[c][f] = h;
            }
            const float b = (bih1[row] + bhh1[row]) * sc;
            cbias[c] = f32x4{b, b, b, b};
        }
    }

    // ---- x prefetch (L0 waves): this lane's seq = quad ----
    const float* xq = x + (size_t)(blockIdx.x * 4 + quad) * TT * 3;
    float xn0 = 0.f, xn1 = 0.f, xn2 = 0.f;
    if (!isL1) { xn0 = xq[0]; xn1 = xq[1]; xn2 = xq[2]; }

    const f32x4 Z = {0.f, 0.f, 0.f, 0.f};
    float cst = 0.0f;    // cell state (layer per role, seq=quad, elem=col)

    // critical-wave priority: L0 is the pole (16 MFMA vs L1's 8, lag-2 slack)
    if (!isL1) __builtin_amdgcn_s_setprio(1);

    __syncthreads();

    // iter it = 0 .. TT+1 in unrolled pairs (cur/prev compile-time).
    // L0: step it (it<TT) + pI(it-1) (it<=TT).  L1: step it-2 (it>=2).
    // ONE barrier per iteration.
    for (int bt = 0; bt <= TT + 1; bt += 2) {
        #pragma unroll
        for (int sub = 0; sub < 2; ++sub) {
            const int it   = bt + sub;
            const int cur  = sub;        // bt even => it&1 == sub
            const int prev = sub ^ 1;

            if (!isL1) {
                if (it <= TT) {
                    // A-frags: h1[it-1] (parity prev), replicated rows
                    const _Float16* hb = h1a[prev] + (l16 & 3) * HSTR + quad * 8;
                    half8 a0 = *(const half8*)hb;
                    half8 a1 = *(const half8*)(hb + 32);

                    const bool doGate = (it < TT);
                    f32x4 acc0[4], acc1[4];
                    float xp0, xp1, xp2, xp3;
                    if (doGate) {
                        // x-projection (prescaled weights): independent of MFMA
                        // results, hidden under the ds_read latency window.
                        const float x0 = xn0, x1 = xn1, x2 = xn2;
                        xp0 = fmaf(wxa[0], x0, fmaf(wxb[0], x1, wxc[0] * x2));
                        xp1 = fmaf(wxa[1], x0, fmaf(wxb[1], x1, wxc[1] * x2));
                        xp2 = fmaf(wxa[2], x0, fmaf(wxb[2], x1, wxc[2] * x2));
                        xp3 = fmaf(wxa[3], x0, fmaf(wxb[3], x1, wxc[3] * x2));
                        const int nt = (it + 1 < TT) ? it + 1 : TT - 1;
                        const float* np = xq + nt * 3;
                        xn0 = np[0]; xn1 = np[1]; xn2 = np[2];

                        // CRITICAL: gate MFMAs first; split accumulators so the
                        // a0/a1 halves complete in parallel (no z-chain dep).
                        #pragma unroll
                        for (int c = 0; c < 4; ++c) {
                            acc0[c] = __builtin_amdgcn_mfma_f32_16x16x32_f16(a0, wA[c][0], cbias[c], 0, 0, 0);
                            acc1[c] = __builtin_amdgcn_mfma_f32_16x16x32_f16(a1, wA[c][1], Z,        0, 0, 0);
                        }
                    }

                    // pI(it-1) = Wih1 . h1[it-1] -> pIbuf[prev]; deadline is the
                    // NEXT iteration's L1 read — issues behind gates, completes
                    // under the VALU activation tail. Stays z-chained.
                    f32x4 accP[4];
                    #pragma unroll
                    for (int c = 0; c < 4; ++c) {
                        f32x4 z = Z;
                        z = __builtin_amdgcn_mfma_f32_16x16x32_f16(a0, wB[c][0], z, 0, 0, 0);
                        z = __builtin_amdgcn_mfma_f32_16x16x32_f16(a1, wB[c][1], z, 0, 0, 0);
                        accP[c] = z;
                    }

                    if (doGate) {
                        float pi = sel4(acc0[0], quad) + sel4(acc1[0], quad) + xp0;
                        float pf = sel4(acc0[1], quad) + sel4(acc1[1], quad) + xp1;
                        float pg = sel4(acc0[2], quad) + sel4(acc1[2], quad) + xp2;
                        float po = sel4(acc0[3], quad) + sel4(acc1[3], quad) + xp3;
                        float iv = sig_p(pi), fv = sig_p(pf);
                        float gv = tanh_p(pg), ov = sig_p(po);
                        cst = fmaf(fv, cst, iv * gv);
                        float th = tanh_p(cst * LOG2E2);
                        h1a[cur][quad * HSTR + col] = (_Float16)(ov * th); // h1[it]
                    }

                    if (quad == 0) {
                        #pragma unroll
                        for (int c = 0; c < 4; ++c)
                            pIbuf[prev][c][col] = make_float4(accP[c][0], accP[c][1],
                                                              accP[c][2], accP[c][3]);
                    }
                }
            } else {
                if (it >= 2) {
                    // L1 step s = it-2: Whh1 . h2[it-3] (parity prev) + pI(s) (pIbuf[cur])
                    const _Float16* hb2 = h2a[prev] + (l16 & 3) * HSTR + quad * 8;
                    half8 a2 = *(const half8*)hb2;
                    half8 a3 = *(const half8*)(hb2 + 32);
                    // partial sums: hoisted ds_reads (written last iteration,
                    // valid since the barrier; <=2-way banks)
                    const float* pb = (const float*)&pIbuf[cur][0][col] + quad;
                    const float pb0 = pb[0 * 256];
                    const float pb1 = pb[1 * 256];
                    const float pb2 = pb[2 * 256];
                    const float pb3 = pb[3 * 256];
                    // split accumulators (parallel MFMA halves)
                    f32x4 acc0[4], acc1[4];
                    #pragma unroll
                    for (int c = 0; c < 4; ++c) {
                        acc0[c] = __builtin_amdgcn_mfma_f32_16x16x32_f16(a2, wA[c][0], cbias[c], 0, 0, 0);
                        acc1[c] = __builtin_amdgcn_mfma_f32_16x16x32_f16(a3, wA[c][1], Z,        0, 0, 0);
                    }
                    float pi = sel4(acc0[0], quad) + sel4(acc1[0], quad) + pb0;
                    float pf = sel4(acc0[1], quad) + sel4(acc1[1], quad) + pb1;
                    float pg = sel4(acc0[2], quad) + sel4(acc1[2], quad) + pb2;
                    float po = sel4(acc0[3], quad) + sel4(acc1[3], quad) + pb3;
                    float iv = sig_p(pi), fv = sig_p(pf);
                    float gv = tanh_p(pg), ov = sig_p(po);
                    cst = fmaf(fv, cst, iv * gv);
                    float hv = ov * tanh_p(cst * LOG2E2);
                    h2a[cur][quad * HSTR + col] = (_Float16)hv;            // h2[it-2]
                    if (it == TT + 1)
                        out[(size_t)(blockIdx.x * 4 + quad) * 64 + col] = hv;
                }
            }
            __syncthreads();
        }
    }
}

extern "C" void kernel_launch(void* const* d_in, const int* in_sizes, int n_in,
                              void* d_out, int out_size, void* d_ws, size_t ws_size,
                              hipStream_t stream) {
    const float* x    = (const float*)d_in[0];
    const float* Wih0 = (const float*)d_in[1];
    const float* Whh0 = (const float*)d_in[2];
    const float* bih0 = (const float*)d_in[3];
    const float* bhh0 = (const float*)d_in[4];
    const float* Wih1 = (const float*)d_in[5];
    const float* Whh1 = (const float*)d_in[6];
    const float* bih1 = (const float*)d_in[7];
    const float* bhh1 = (const float*)d_in[8];
    float* out = (float*)d_out;

    // 512 sequences / 4 per block = 128 blocks; 512 threads (8 waves, 2/SIMD).
    lstm2_fused<<<128, 512, 0, stream>>>(x, Wih0, Whh0, bih0, bhh0,
                                         Wih1, Whh1, bih1, bhh1, out);
}

// Round 7
// 1055.718 us; speedup vs baseline: 1.0157x; 1.0157x over previous
//
#include <hip/hip_runtime.h>
#include <math.h>

// BiometricLSTM: 2-layer LSTM, B=512, T=2048, I=3, H=64, fp32 in/out. Output = final h2 (B,64).
//
// R24: R20 (best, 1064.1 us) + ONE change: the in-loop __syncthreads() is
// replaced by a raw s_barrier preceded by s_waitcnt lgkmcnt(0) only.
// Theory: __syncthreads compiles to "s_waitcnt vmcnt(0) lgkmcnt(0); s_barrier".
// The vmcnt(0) drain forces the L0 waves' 3 per-iter global x-prefetch loads
// (consumer: NEXT iteration) to complete before THIS iteration's barrier,
// putting 200-900cy of global latency on the 2050-iteration critical chain.
// All inter-wave communication here is via LDS (h1a/h2a/pIbuf), so only
// lgkmcnt(0) is semantically required. sched_barrier(0) fences pin the asm
// (hipcc hoists around inline-asm waitcnt otherwise — guide rule #18).
// R23 post-mortem: split-acc + prescale + setprio bundle was neutral (+0.8%);
// split-acc's extra sel4/cndmask merges ate the MFMA-latency saving
// (VALUBusy 24.6->27.5). Reverted; R20 structure kept verbatim.
//
// R20 recap: 128 blocks x 512 thr, split waves (L0 = Whh0+Wih1 16 MFMA,
// L1 = Whh1 8 MFMA, lag 2), gates-before-pI issue order, unroll-2
// (compile-time parity), M=4 replicated rows, quad-selected in-lane update,
// HSTR=80, z-chained MFMA pairs with bias in C, rcp-based activations,
// x-projection hoisted pre-MFMA, hoisted pIbuf reads, ONE barrier/iter,
// f16 weights/h + f32 accum.
// Parities: h1[t]@t&1; h2[t]@t&1; pIbuf write@prev / read@cur disjoint.

typedef _Float16 half8 __attribute__((ext_vector_type(8)));
typedef float    f32x4 __attribute__((ext_vector_type(4)));

constexpr int TT = 2048;
constexpr int HSTR = 80;   // h row stride in halves (160 B)

__device__ __forceinline__ float fast_sigmoid(float x) {
    // 1/(1+e^-x) with single v_rcp (no IEEE div expansion)
    return __builtin_amdgcn_rcpf(1.0f + __expf(-x));
}
// tanh = 1 - 2/(exp(2x)+1): saturates correctly at +-inf
__device__ __forceinline__ float fast_tanh(float x) {
    return 1.0f - 2.0f * __builtin_amdgcn_rcpf(__expf(2.0f * x) + 1.0f);
}
// select component q (lane's quad) from an f32x4 accumulator
__device__ __forceinline__ float sel4(f32x4 v, int q) {
    float r = v[0];
    r = (q == 1) ? v[1] : r;
    r = (q == 2) ? v[2] : r;
    r = (q == 3) ? v[3] : r;
    return r;
}

// Barrier with LDS-only drain: s_waitcnt lgkmcnt(0) + s_barrier.
// Deliberately does NOT drain vmcnt — in-flight global loads (x prefetch)
// stay in flight across the barrier. sched_barrier(0) pins placement.
__device__ __forceinline__ void lds_barrier() {
    __builtin_amdgcn_sched_barrier(0);
    asm volatile("s_waitcnt lgkmcnt(0)" ::: "memory");
    __builtin_amdgcn_s_barrier();
    __builtin_amdgcn_sched_barrier(0);
}

__global__ __launch_bounds__(512) void lstm2_fused(
    const float* __restrict__ x,
    const float* __restrict__ Wih0, const float* __restrict__ Whh0,
    const float* __restrict__ bih0, const float* __restrict__ bhh0,
    const float* __restrict__ Wih1, const float* __restrict__ Whh1,
    const float* __restrict__ bih1, const float* __restrict__ bhh1,
    float* __restrict__ out)
{
    __shared__ __align__(16) _Float16 h1a[2][4 * HSTR];   // [parity][seq*HSTR + elem]
    __shared__ __align__(16) _Float16 h2a[2][4 * HSTR];
    __shared__ __align__(16) float4   pIbuf[2][4][64];    // [stepParity][class][col] = 4 seqs

    const int tid  = threadIdx.x;
    const int lane = tid & 63;
    const int wid  = tid >> 6;
    const int quad = lane >> 4;
    const int l16  = lane & 15;
    const bool isL1 = (wid >= 4);
    const int col  = (wid & 3) * 16 + l16;   // gate-elem column this lane owns per class

    // ---- zero h double-buffers ----
    for (int i = tid; i < 2 * 4 * HSTR; i += 512) {
        ((_Float16*)h1a)[i] = (_Float16)0.0f;
        ((_Float16*)h2a)[i] = (_Float16)0.0f;
    }

    // ---- weights (B-frags, f16): lane holds W[c*64+col][f*32 + quad*8 .. +8] ----
    half8 wA[4][2];      // L0 waves: Whh0 | L1 waves: Whh1
    half8 wB[4][2];      // L0 waves only: Wih1
    f32x4 cbias[4];      // bias splat, MFMA C-init (L0: bias0; L1: bias1)
    float wxa[4], wxb[4], wxc[4];            // L0 only
    #pragma unroll
    for (int c = 0; c < 4; ++c) {
        const int row = c * 64 + col;
        if (!isL1) {
            #pragma unroll
            for (int f = 0; f < 2; ++f) {
                const float* p = Whh0 + (size_t)row * 64 + f * 32 + quad * 8;
                half8 h;
                #pragma unroll
                for (int u = 0; u < 8; ++u) h[u] = (_Float16)p[u];
                wA[c][f] = h;
                const float* q = Wih1 + (size_t)row * 64 + f * 32 + quad * 8;
                half8 g;
                #pragma unroll
                for (int u = 0; u < 8; ++u) g[u] = (_Float16)q[u];
                wB[c][f] = g;
            }
            const float b = bih0[row] + bhh0[row];
            cbias[c] = f32x4{b, b, b, b};
            wxa[c] = Wih0[row*3+0]; wxb[c] = Wih0[row*3+1]; wxc[c] = Wih0[row*3+2];
        } else {
            #pragma unroll
            for (int f = 0; f < 2; ++f) {
                const float* p = Whh1 + (size_t)row * 64 + f * 32 + quad * 8;
                half8 h;
                #pragma unroll
                for (int u = 0; u < 8; ++u) h[u] = (_Float16)p[u];
                wA[c][f] = h;
            }
            const float b = bih1[row] + bhh1[row];
            cbias[c] = f32x4{b, b, b, b};
        }
    }

    // ---- x prefetch (L0 waves): this lane's seq = quad ----
    const float* xq = x + (size_t)(blockIdx.x * 4 + quad) * TT * 3;
    float xn0 = 0.f, xn1 = 0.f, xn2 = 0.f;
    if (!isL1) { xn0 = xq[0]; xn1 = xq[1]; xn2 = xq[2]; }

    float cst = 0.0f;    // cell state (layer per role, seq=quad, elem=col)

    __syncthreads();   // init barrier: full drain is fine here (once)

    // iter it = 0 .. TT+1 in unrolled pairs (cur/prev compile-time).
    // L0: step it (it<TT) + pI(it-1) (it<=TT).  L1: step it-2 (it>=2).
    // ONE lds_barrier per iteration.
    for (int bt = 0; bt <= TT + 1; bt += 2) {
        #pragma unroll
        for (int sub = 0; sub < 2; ++sub) {
            const int it   = bt + sub;
            const int cur  = sub;        // bt even => it&1 == sub
            const int prev = sub ^ 1;

            if (!isL1) {
                if (it <= TT) {
                    // A-frags: h1[it-1] (parity prev), replicated rows
                    const _Float16* hb = h1a[prev] + (l16 & 3) * HSTR + quad * 8;
                    half8 a0 = *(const half8*)hb;
                    half8 a1 = *(const half8*)(hb + 32);

                    const bool doGate = (it < TT);
                    f32x4 acc[4];
                    float xp0, xp1, xp2, xp3;
                    if (doGate) {
                        // x-projection: independent of MFMA results, hidden
                        // under the ds_read latency window.
                        const float x0 = xn0, x1 = xn1, x2 = xn2;
                        xp0 = fmaf(wxa[0], x0, fmaf(wxb[0], x1, wxc[0] * x2));
                        xp1 = fmaf(wxa[1], x0, fmaf(wxb[1], x1, wxc[1] * x2));
                        xp2 = fmaf(wxa[2], x0, fmaf(wxb[2], x1, wxc[2] * x2));
                        xp3 = fmaf(wxa[3], x0, fmaf(wxb[3], x1, wxc[3] * x2));
                        const int nt = (it + 1 < TT) ? it + 1 : TT - 1;
                        const float* np = xq + nt * 3;
                        xn0 = np[0]; xn1 = np[1]; xn2 = np[2];

                        // CRITICAL: gate MFMAs issue first (in-order MFMA pipe).
                        #pragma unroll
                        for (int c = 0; c < 4; ++c) {
                            f32x4 z = cbias[c];
                            z = __builtin_amdgcn_mfma_f32_16x16x32_f16(a0, wA[c][0], z, 0, 0, 0);
                            z = __builtin_amdgcn_mfma_f32_16x16x32_f16(a1, wA[c][1], z, 0, 0, 0);
                            acc[c] = z;
                        }
                    }

                    // pI(it-1) = Wih1 . h1[it-1] -> pIbuf[prev]; deadline is the
                    // NEXT iteration's L1 read — issues behind gates, completes
                    // under the VALU activation tail.
                    f32x4 accP[4];
                    #pragma unroll
                    for (int c = 0; c < 4; ++c) {
                        f32x4 z = {0.f, 0.f, 0.f, 0.f};
                        z = __builtin_amdgcn_mfma_f32_16x16x32_f16(a0, wB[c][0], z, 0, 0, 0);
                        z = __builtin_amdgcn_mfma_f32_16x16x32_f16(a1, wB[c][1], z, 0, 0, 0);
                        accP[c] = z;
                    }

                    if (doGate) {
                        float pi = sel4(acc[0], quad) + xp0;
                        float pf = sel4(acc[1], quad) + xp1;
                        float pg = sel4(acc[2], quad) + xp2;
                        float po = sel4(acc[3], quad) + xp3;
                        float iv = fast_sigmoid(pi), fv = fast_sigmoid(pf);
                        float gv = fast_tanh(pg),    ov = fast_sigmoid(po);
                        cst = fmaf(fv, cst, iv * gv);
                        h1a[cur][quad * HSTR + col] = (_Float16)(ov * fast_tanh(cst)); // h1[it]
                    }

                    if (quad == 0) {
                        #pragma unroll
                        for (int c = 0; c < 4; ++c)
                            pIbuf[prev][c][col] = make_float4(accP[c][0], accP[c][1],
                                                              accP[c][2], accP[c][3]);
                    }
                }
            } else {
                if (it >= 2) {
                    // L1 step s = it-2: Whh1 . h2[it-3] (parity prev) + pI(s) (pIbuf[cur])
                    const _Float16* hb2 = h2a[prev] + (l16 & 3) * HSTR + quad * 8;
                    half8 a2 = *(const half8*)hb2;
                    half8 a3 = *(const half8*)(hb2 + 32);
                    // partial sums: hoisted ds_reads (written last iteration,
                    // valid since the barrier; <=2-way banks)
                    const float* pb = (const float*)&pIbuf[cur][0][col] + quad;
                    const float pb0 = pb[0 * 256];
                    const float pb1 = pb[1 * 256];
                    const float pb2 = pb[2 * 256];
                    const float pb3 = pb[3 * 256];
                    f32x4 acc[4];
                    #pragma unroll
                    for (int c = 0; c < 4; ++c) {
                        f32x4 z = cbias[c];
                        z = __builtin_amdgcn_mfma_f32_16x16x32_f16(a2, wA[c][0], z, 0, 0, 0);
                        z = __builtin_amdgcn_mfma_f32_16x16x32_f16(a3, wA[c][1], z, 0, 0, 0);
                        acc[c] = z;
                    }
                    float pi = sel4(acc[0], quad) + pb0;
                    float pf = sel4(acc[1], quad) + pb1;
                    float pg = sel4(acc[2], quad) + pb2;
                    float po = sel4(acc[3], quad) + pb3;
                    float iv = fast_sigmoid(pi), fv = fast_sigmoid(pf);
                    float gv = fast_tanh(pg),    ov = fast_sigmoid(po);
                    cst = fmaf(fv, cst, iv * gv);
                    float hv = ov * fast_tanh(cst);
                    h2a[cur][quad * HSTR + col] = (_Float16)hv;            // h2[it-2]
                    if (it == TT + 1)
                        out[(size_t)(blockIdx.x * 4 + quad) * 64 + col] = hv;
                }
            }
            lds_barrier();   // LDS-only drain: x prefetch stays in flight
        }
    }
}

extern "C" void kernel_launch(void* const* d_in, const int* in_sizes, int n_in,
                              void* d_out, int out_size, void* d_ws, size_t ws_size,
                              hipStream_t stream) {
    const float* x    = (const float*)d_in[0];
    const float* Wih0 = (const float*)d_in[1];
    const float* Whh0 = (const float*)d_in[2];
    const float* bih0 = (const float*)d_in[3];
    const float* bhh0 = (const float*)d_in[4];
    const float* Wih1 = (const float*)d_in[5];
    const float* Whh1 = (const float*)d_in[6];
    const float* bih1 = (const float*)d_in[7];
    const float* bhh1 = (const float*)d_in[8];
    float* out = (float*)d_out;

    // 512 sequences / 4 per block = 128 blocks; 512 threads (8 waves, 2/SIMD).
    lstm2_fused<<<128, 512, 0, stream>>>(x, Wih0, Whh0, bih0, bhh0,
                                         Wih1, Whh1, bih1, bhh1, out);
}

// Round 8
// 990.665 us; speedup vs baseline: 1.0823x; 1.0657x over previous
//
#include <hip/hip_runtime.h>
#include <math.h>

// BiometricLSTM: 2-layer LSTM, B=512, T=2048, I=3, H=64, fp32 in/out. Output = final h2 (B,64).
//
// R25: R24 (best, 1055.7 us) + pole rebalance: move ALL of pI = Wih1.h1 from the
// L0 waves (critical pole: was 16 MFMA + pIbuf write) to the L1 waves (slack:
// was 8 MFMA + barrier spin), and DELETE the pIbuf LDS round-trip entirely.
// Key insight: with the replicated-row layout, C/D reg j of every lane = seq j,
// so L1 computing Wih1.h1 for its own 16 columns yields sel4(accQ, quad) =
// exactly the (seq=quad, col) partial that pIbuf delivered via LDS — no
// transpose needed. accQ lives in registers, double-buffered by the unroll-2
// parity (compile-time indices, no scratch).
//   L0/iter: ds_read a0,a1 -> 8 gate MFMAs -> tail -> h1 write.  (pole -40cy issue)
//   L1/iter it: reads h2[it-3] frags + h1[it-1] frags; 8 gate MFMAs (critical,
//   issue first) then 8 pI MFMAs -> accQ[sub] (off-critical: consumed NEXT iter
//   as accQ[sub^1]). Gates use acc + accQold; pIbuf, pb reads, quad==0 writes gone.
// Timing: accQ_j = pI(j-1) computed at iter j from h1a[prev]=h1[j-1]; consumed at
// iter j+1 for step j-1. doQ: 1<=it<=TT. Arithmetic bit-identical to R24 (same
// z-chain order; pI enters the gate sum as the same f32 value) -> absmax canary
// 4.88e-4 must hold. LDS 10752->2560B.
// R24 post-mortem: lds_barrier (lgkmcnt-only drain) was neutral (-0.8%) — the
// vmcnt-drain theory refuted; x-loads retire in time. lds_barrier kept.
// All else R20/R24 verbatim: 128 blocks x 512 thr, gates-before-pI issue order,
// unroll-2 compile-time parity, M=4 replicated rows, quad-selected update,
// HSTR=80, z-chained MFMA pairs bias-in-C, rcp activations, x-proj hoisted,
// ONE lds_barrier/iter, f16 weights/h + f32 accum.
// Parities: h1[t]@t&1; h2[t]@t&1; accQ write@sub / read@sub^1.

typedef _Float16 half8 __attribute__((ext_vector_type(8)));
typedef float    f32x4 __attribute__((ext_vector_type(4)));

constexpr int TT = 2048;
constexpr int HSTR = 80;   // h row stride in halves (160 B)

__device__ __forceinline__ float fast_sigmoid(float x) {
    // 1/(1+e^-x) with single v_rcp (no IEEE div expansion)
    return __builtin_amdgcn_rcpf(1.0f + __expf(-x));
}
// tanh = 1 - 2/(exp(2x)+1): saturates correctly at +-inf
__device__ __forceinline__ float fast_tanh(float x) {
    return 1.0f - 2.0f * __builtin_amdgcn_rcpf(__expf(2.0f * x) + 1.0f);
}
// select component q (lane's quad) from an f32x4 accumulator
__device__ __forceinline__ float sel4(f32x4 v, int q) {
    float r = v[0];
    r = (q == 1) ? v[1] : r;
    r = (q == 2) ? v[2] : r;
    r = (q == 3) ? v[3] : r;
    return r;
}

// Barrier with LDS-only drain: s_waitcnt lgkmcnt(0) + s_barrier.
// Does NOT drain vmcnt — in-flight global x-prefetch loads stay in flight.
__device__ __forceinline__ void lds_barrier() {
    __builtin_amdgcn_sched_barrier(0);
    asm volatile("s_waitcnt lgkmcnt(0)" ::: "memory");
    __builtin_amdgcn_s_barrier();
    __builtin_amdgcn_sched_barrier(0);
}

__global__ __launch_bounds__(512) void lstm2_fused(
    const float* __restrict__ x,
    const float* __restrict__ Wih0, const float* __restrict__ Whh0,
    const float* __restrict__ bih0, const float* __restrict__ bhh0,
    const float* __restrict__ Wih1, const float* __restrict__ Whh1,
    const float* __restrict__ bih1, const float* __restrict__ bhh1,
    float* __restrict__ out)
{
    __shared__ __align__(16) _Float16 h1a[2][4 * HSTR];   // [parity][seq*HSTR + elem]
    __shared__ __align__(16) _Float16 h2a[2][4 * HSTR];

    const int tid  = threadIdx.x;
    const int lane = tid & 63;
    const int wid  = tid >> 6;
    const int quad = lane >> 4;
    const int l16  = lane & 15;
    const bool isL1 = (wid >= 4);
    const int col  = (wid & 3) * 16 + l16;   // gate-elem column this lane owns per class

    // ---- zero h double-buffers ----
    for (int i = tid; i < 2 * 4 * HSTR; i += 512) {
        ((_Float16*)h1a)[i] = (_Float16)0.0f;
        ((_Float16*)h2a)[i] = (_Float16)0.0f;
    }

    // ---- weights (B-frags, f16): lane holds W[c*64+col][f*32 + quad*8 .. +8] ----
    half8 wA[4][2];      // L0 waves: Whh0 | L1 waves: Whh1
    half8 wB[4][2];      // L1 waves only: Wih1  (moved from L0 in R25)
    f32x4 cbias[4];      // bias splat, MFMA C-init (L0: bias0; L1: bias1)
    float wxa[4], wxb[4], wxc[4];            // L0 only
    #pragma unroll
    for (int c = 0; c < 4; ++c) {
        const int row = c * 64 + col;
        if (!isL1) {
            #pragma unroll
            for (int f = 0; f < 2; ++f) {
                const float* p = Whh0 + (size_t)row * 64 + f * 32 + quad * 8;
                half8 h;
                #pragma unroll
                for (int u = 0; u < 8; ++u) h[u] = (_Float16)p[u];
                wA[c][f] = h;
            }
            const float b = bih0[row] + bhh0[row];
            cbias[c] = f32x4{b, b, b, b};
            wxa[c] = Wih0[row*3+0]; wxb[c] = Wih0[row*3+1]; wxc[c] = Wih0[row*3+2];
        } else {
            #pragma unroll
            for (int f = 0; f < 2; ++f) {
                const float* p = Whh1 + (size_t)row * 64 + f * 32 + quad * 8;
                half8 h;
                #pragma unroll
                for (int u = 0; u < 8; ++u) h[u] = (_Float16)p[u];
                wA[c][f] = h;
                const float* q = Wih1 + (size_t)row * 64 + f * 32 + quad * 8;
                half8 g;
                #pragma unroll
                for (int u = 0; u < 8; ++u) g[u] = (_Float16)q[u];
                wB[c][f] = g;
            }
            const float b = bih1[row] + bhh1[row];
            cbias[c] = f32x4{b, b, b, b};
        }
    }

    // ---- x prefetch (L0 waves): this lane's seq = quad ----
    const float* xq = x + (size_t)(blockIdx.x * 4 + quad) * TT * 3;
    float xn0 = 0.f, xn1 = 0.f, xn2 = 0.f;
    if (!isL1) { xn0 = xq[0]; xn1 = xq[1]; xn2 = xq[2]; }

    const f32x4 Z = {0.f, 0.f, 0.f, 0.f};
    float cst = 0.0f;    // cell state (layer per role, seq=quad, elem=col)

    // L1: pI double-buffer in registers; accQ[sub] written at parity sub,
    // read at sub^1. Indices are compile-time after the unroll (rule #20).
    f32x4 accQ[2][4];
    #pragma unroll
    for (int s = 0; s < 2; ++s)
        #pragma unroll
        for (int c = 0; c < 4; ++c) accQ[s][c] = Z;

    __syncthreads();   // init barrier: full drain fine here (once)

    // iter it = 0 .. TT+1 in unrolled pairs (cur/prev compile-time).
    // L0: step it (it<TT).  L1: gates for step it-2 (it>=2) + pI(it-1) (1<=it<=TT).
    // ONE lds_barrier per iteration.
    for (int bt = 0; bt <= TT + 1; bt += 2) {
        #pragma unroll
        for (int sub = 0; sub < 2; ++sub) {
            const int it   = bt + sub;
            const int cur  = sub;        // bt even => it&1 == sub
            const int prev = sub ^ 1;

            if (!isL1) {
                if (it < TT) {
                    // A-frags: h1[it-1] (parity prev), replicated rows
                    const _Float16* hb = h1a[prev] + (l16 & 3) * HSTR + quad * 8;
                    half8 a0 = *(const half8*)hb;
                    half8 a1 = *(const half8*)(hb + 32);

                    // x-projection: independent of MFMA results, hidden
                    // under the ds_read latency window.
                    const float x0 = xn0, x1 = xn1, x2 = xn2;
                    float xp0 = fmaf(wxa[0], x0, fmaf(wxb[0], x1, wxc[0] * x2));
                    float xp1 = fmaf(wxa[1], x0, fmaf(wxb[1], x1, wxc[1] * x2));
                    float xp2 = fmaf(wxa[2], x0, fmaf(wxb[2], x1, wxc[2] * x2));
                    float xp3 = fmaf(wxa[3], x0, fmaf(wxb[3], x1, wxc[3] * x2));
                    const int nt = (it + 1 < TT) ? it + 1 : TT - 1;
                    const float* np = xq + nt * 3;
                    xn0 = np[0]; xn1 = np[1]; xn2 = np[2];

                    // L0 gates: Whh0 . h1[it-1] + bias (in C) — the pole.
                    f32x4 acc[4];
                    #pragma unroll
                    for (int c = 0; c < 4; ++c) {
                        f32x4 z = cbias[c];
                        z = __builtin_amdgcn_mfma_f32_16x16x32_f16(a0, wA[c][0], z, 0, 0, 0);
                        z = __builtin_amdgcn_mfma_f32_16x16x32_f16(a1, wA[c][1], z, 0, 0, 0);
                        acc[c] = z;
                    }
                    float pi = sel4(acc[0], quad) + xp0;
                    float pf = sel4(acc[1], quad) + xp1;
                    float pg = sel4(acc[2], quad) + xp2;
                    float po = sel4(acc[3], quad) + xp3;
                    float iv = fast_sigmoid(pi), fv = fast_sigmoid(pf);
                    float gv = fast_tanh(pg),    ov = fast_sigmoid(po);
                    cst = fmaf(fv, cst, iv * gv);
                    h1a[cur][quad * HSTR + col] = (_Float16)(ov * fast_tanh(cst)); // h1[it]
                }
            } else {
                const bool doG = (it >= 2);             // gates for step it-2
                const bool doQ = (it >= 1 && it <= TT); // pI(it-1) for next iter

                // ds_reads first (both frag sets issue together)
                half8 a2, a3, b0, b1;
                if (doG) {
                    const _Float16* hb2 = h2a[prev] + (l16 & 3) * HSTR + quad * 8;
                    a2 = *(const half8*)hb2;
                    a3 = *(const half8*)(hb2 + 32);
                }
                if (doQ) {
                    const _Float16* hb1 = h1a[prev] + (l16 & 3) * HSTR + quad * 8;
                    b0 = *(const half8*)hb1;
                    b1 = *(const half8*)(hb1 + 32);
                }

                // CRITICAL: gate MFMAs issue first (in-order MFMA pipe).
                f32x4 acc[4];
                if (doG) {
                    #pragma unroll
                    for (int c = 0; c < 4; ++c) {
                        f32x4 z = cbias[c];
                        z = __builtin_amdgcn_mfma_f32_16x16x32_f16(a2, wA[c][0], z, 0, 0, 0);
                        z = __builtin_amdgcn_mfma_f32_16x16x32_f16(a3, wA[c][1], z, 0, 0, 0);
                        acc[c] = z;
                    }
                }
                // pI(it-1) = Wih1 . h1[it-1] -> accQ[sub] (registers, consumed
                // NEXT iteration as accQ[sub^1]). Off-critical; issues behind
                // gates, completes under the VALU activation tail.
                if (doQ) {
                    #pragma unroll
                    for (int c = 0; c < 4; ++c) {
                        f32x4 z = Z;
                        z = __builtin_amdgcn_mfma_f32_16x16x32_f16(b0, wB[c][0], z, 0, 0, 0);
                        z = __builtin_amdgcn_mfma_f32_16x16x32_f16(b1, wB[c][1], z, 0, 0, 0);
                        accQ[sub][c] = z;
                    }
                }

                if (doG) {
                    // gates = Whh1.h2[it-3] + bias + pI(it-2) (accQ old buffer)
                    float pi = sel4(acc[0], quad) + sel4(accQ[prev][0], quad);
                    float pf = sel4(acc[1], quad) + sel4(accQ[prev][1], quad);
                    float pg = sel4(acc[2], quad) + sel4(accQ[prev][2], quad);
                    float po = sel4(acc[3], quad) + sel4(accQ[prev][3], quad);
                    float iv = fast_sigmoid(pi), fv = fast_sigmoid(pf);
                    float gv = fast_tanh(pg),    ov = fast_sigmoid(po);
                    cst = fmaf(fv, cst, iv * gv);
                    float hv = ov * fast_tanh(cst);
                    h2a[cur][quad * HSTR + col] = (_Float16)hv;            // h2[it-2]
                    if (it == TT + 1)
                        out[(size_t)(blockIdx.x * 4 + quad) * 64 + col] = hv;
                }
            }
            lds_barrier();   // LDS-only drain; x prefetch stays in flight
        }
    }
}

extern "C" void kernel_launch(void* const* d_in, const int* in_sizes, int n_in,
                              void* d_out, int out_size, void* d_ws, size_t ws_size,
                              hipStream_t stream) {
    const float* x    = (const float*)d_in[0];
    const float* Wih0 = (const float*)d_in[1];
    const float* Whh0 = (const float*)d_in[2];
    const float* bih0 = (const float*)d_in[3];
    const float* bhh0 = (const float*)d_in[4];
    const float* Wih1 = (const float*)d_in[5];
    const float* Whh1 = (const float*)d_in[6];
    const float* bih1 = (const float*)d_in[7];
    const float* bhh1 = (const float*)d_in[8];
    float* out = (float*)d_out;

    // 512 sequences / 4 per block = 128 blocks; 512 threads (8 waves, 2/SIMD).
    lstm2_fused<<<128, 512, 0, stream>>>(x, Wih0, Whh0, bih0, bhh0,
                                         Wih1, Whh1, bih1, bhh1, out);
}

// Round 9
// 941.758 us; speedup vs baseline: 1.1386x; 1.0519x over previous
//
#include <hip/hip_runtime.h>
#include <math.h>

// BiometricLSTM: 2-layer LSTM, B=512, T=2048, I=3, H=64, fp32 in/out. Output = final h2 (B,64).
//
// R26: R25 (best, 990.7 us) + three tail/window micro-cuts. Structure unchanged.
//  (1) log2e prescale (isolated; R23 bundled it with the harmful split-acc):
//      all gate weights/biases scaled at load by log2e (classes i,f,o) or
//      2*log2e (class g) — exact per-class rescale. Activations become bare
//      v_exp_f32 (exp2; negate is a free input modifier): sigmoid=rcp(1+exp2(-y)),
//      tanh_g=1-2*rcp(exp2(y)+1); tanh(cst) = 1 mul (LOG2E2) + exp2 (was 2 muls).
//      Cuts ~2 muls from the serial c-chain + 5 VALU issues per step per role.
//  (2) L1 read-window fill: hoist the 4 sel4(accQ[prev]) (12 cndmasks) into the
//      ds_read latency window, before the gate MFMAs. L1 tail becomes
//      sel4(acc)+qp (1 add); accQ[prev] regs die earlier.
//  (3) sel4 as a 2-level tree ((q&1) pair-selects, then (q&2)): depth 2 vs the
//      serial 3-cndmask chain; level-1 cndmasks share one vcc.
// R25 recap (all kept): split waves L0=Whh0 8 MFMA / L1=Whh1+Wih1 16 MFMA lag-2;
// pI computed by L1 into registers accQ[2][4] (write@sub, read@sub^1), no pIbuf,
// LDS 2560B, bank conflicts 0; gates-before-pI issue order; unroll-2 compile-time
// parity; M=4 replicated rows; quad-selected in-lane update; HSTR=80; z-chained
// MFMA pairs bias-in-C; x-proj hoisted into L0's read window; lds_barrier
// (lgkmcnt-only drain) once per iter; f16 weights/h + f32 accum.
// Parities: h1[t]@t&1; h2[t]@t&1; accQ write@sub / read@sub^1.

typedef _Float16 half8 __attribute__((ext_vector_type(8)));
typedef float    f32x4 __attribute__((ext_vector_type(4)));

constexpr int TT = 2048;
constexpr int HSTR = 80;   // h row stride in halves (160 B)

#define LOG2E  1.44269504088896340736f
#define LOG2E2 2.88539008177792681472f

// y = x*log2e applied upstream: sigmoid(x) = 1/(1+2^-y)
__device__ __forceinline__ float sig_p(float y) {
    return __builtin_amdgcn_rcpf(1.0f + __builtin_amdgcn_exp2f(-y));
}
// y = x*2log2e applied upstream: tanh(x) = 1 - 2/(2^y + 1); saturates at +-inf
__device__ __forceinline__ float tanh_p(float y) {
    return 1.0f - 2.0f * __builtin_amdgcn_rcpf(__builtin_amdgcn_exp2f(y) + 1.0f);
}
// select component q (lane's quad) from an f32x4 accumulator — 2-level tree
__device__ __forceinline__ float sel4(f32x4 v, int q) {
    float lo = (q & 1) ? v[1] : v[0];
    float hi = (q & 1) ? v[3] : v[2];
    return (q & 2) ? hi : lo;
}

// Barrier with LDS-only drain: s_waitcnt lgkmcnt(0) + s_barrier.
// Does NOT drain vmcnt — in-flight global x-prefetch loads stay in flight.
__device__ __forceinline__ void lds_barrier() {
    __builtin_amdgcn_sched_barrier(0);
    asm volatile("s_waitcnt lgkmcnt(0)" ::: "memory");
    __builtin_amdgcn_s_barrier();
    __builtin_amdgcn_sched_barrier(0);
}

__global__ __launch_bounds__(512) void lstm2_fused(
    const float* __restrict__ x,
    const float* __restrict__ Wih0, const float* __restrict__ Whh0,
    const float* __restrict__ bih0, const float* __restrict__ bhh0,
    const float* __restrict__ Wih1, const float* __restrict__ Whh1,
    const float* __restrict__ bih1, const float* __restrict__ bhh1,
    float* __restrict__ out)
{
    __shared__ __align__(16) _Float16 h1a[2][4 * HSTR];   // [parity][seq*HSTR + elem]
    __shared__ __align__(16) _Float16 h2a[2][4 * HSTR];

    const int tid  = threadIdx.x;
    const int lane = tid & 63;
    const int wid  = tid >> 6;
    const int quad = lane >> 4;
    const int l16  = lane & 15;
    const bool isL1 = (wid >= 4);
    const int col  = (wid & 3) * 16 + l16;   // gate-elem column this lane owns per class

    // ---- zero h double-buffers ----
    for (int i = tid; i < 2 * 4 * HSTR; i += 512) {
        ((_Float16*)h1a)[i] = (_Float16)0.0f;
        ((_Float16*)h2a)[i] = (_Float16)0.0f;
    }

    // ---- weights (B-frags, f16), log2e-prescaled per gate class ----
    // class c: 0=i 1=f 2=g 3=o; scale = log2e (sigmoid) or 2*log2e (tanh g)
    half8 wA[4][2];      // L0 waves: Whh0 | L1 waves: Whh1
    half8 wB[4][2];      // L1 waves only: Wih1
    f32x4 cbias[4];      // bias splat (prescaled), MFMA C-init
    float wxa[4], wxb[4], wxc[4];            // L0 only (prescaled)
    #pragma unroll
    for (int c = 0; c < 4; ++c) {
        const int row = c * 64 + col;
        const float sc = (c == 2) ? LOG2E2 : LOG2E;
        if (!isL1) {
            #pragma unroll
            for (int f = 0; f < 2; ++f) {
                const float* p = Whh0 + (size_t)row * 64 + f * 32 + quad * 8;
                half8 h;
                #pragma unroll
                for (int u = 0; u < 8; ++u) h[u] = (_Float16)(p[u] * sc);
                wA[c][f] = h;
            }
            const float b = (bih0[row] + bhh0[row]) * sc;
            cbias[c] = f32x4{b, b, b, b};
            wxa[c] = Wih0[row*3+0] * sc;
            wxb[c] = Wih0[row*3+1] * sc;
            wxc[c] = Wih0[row*3+2] * sc;
        } else {
            #pragma unroll
            for (int f = 0; f < 2; ++f) {
                const float* p = Whh1 + (size_t)row * 64 + f * 32 + quad * 8;
                half8 h;
                #pragma unroll
                for (int u = 0; u < 8; ++u) h[u] = (_Float16)(p[u] * sc);
                wA[c][f] = h;
                const float* q = Wih1 + (size_t)row * 64 + f * 32 + quad * 8;
                half8 g;
                #pragma unroll
                for (int u = 0; u < 8; ++u) g[u] = (_Float16)(q[u] * sc);
                wB[c][f] = g;
            }
            const float b = (bih1[row] + bhh1[row]) * sc;
            cbias[c] = f32x4{b, b, b, b};
        }
    }

    // ---- x prefetch (L0 waves): this lane's seq = quad ----
    const float* xq = x + (size_t)(blockIdx.x * 4 + quad) * TT * 3;
    float xn0 = 0.f, xn1 = 0.f, xn2 = 0.f;
    if (!isL1) { xn0 = xq[0]; xn1 = xq[1]; xn2 = xq[2]; }

    const f32x4 Z = {0.f, 0.f, 0.f, 0.f};
    float cst = 0.0f;    // cell state (layer per role, seq=quad, elem=col)

    // L1: pI double-buffer in registers; accQ[sub] written at parity sub,
    // read at sub^1. Indices are compile-time after the unroll (rule #20).
    f32x4 accQ[2][4];
    #pragma unroll
    for (int s = 0; s < 2; ++s)
        #pragma unroll
        for (int c = 0; c < 4; ++c) accQ[s][c] = Z;

    __syncthreads();   // init barrier: full drain fine here (once)

    // iter it = 0 .. TT+1 in unrolled pairs (cur/prev compile-time).
    // L0: step it (it<TT).  L1: gates for step it-2 (it>=2) + pI(it-1) (1<=it<=TT).
    // ONE lds_barrier per iteration.
    for (int bt = 0; bt <= TT + 1; bt += 2) {
        #pragma unroll
        for (int sub = 0; sub < 2; ++sub) {
            const int it   = bt + sub;
            const int cur  = sub;        // bt even => it&1 == sub
            const int prev = sub ^ 1;

            if (!isL1) {
                if (it < TT) {
                    // A-frags: h1[it-1] (parity prev), replicated rows
                    const _Float16* hb = h1a[prev] + (l16 & 3) * HSTR + quad * 8;
                    half8 a0 = *(const half8*)hb;
                    half8 a1 = *(const half8*)(hb + 32);

                    // x-projection (prescaled): independent of MFMA results,
                    // fills the ds_read latency window.
                    const float x0 = xn0, x1 = xn1, x2 = xn2;
                    float xp0 = fmaf(wxa[0], x0, fmaf(wxb[0], x1, wxc[0] * x2));
                    float xp1 = fmaf(wxa[1], x0, fmaf(wxb[1], x1, wxc[1] * x2));
                    float xp2 = fmaf(wxa[2], x0, fmaf(wxb[2], x1, wxc[2] * x2));
                    float xp3 = fmaf(wxa[3], x0, fmaf(wxb[3], x1, wxc[3] * x2));
                    const int nt = (it + 1 < TT) ? it + 1 : TT - 1;
                    const float* np = xq + nt * 3;
                    xn0 = np[0]; xn1 = np[1]; xn2 = np[2];

                    // L0 gates: Whh0 . h1[it-1] + bias (in C) — the pole.
                    f32x4 acc[4];
                    #pragma unroll
                    for (int c = 0; c < 4; ++c) {
                        f32x4 z = cbias[c];
                        z = __builtin_amdgcn_mfma_f32_16x16x32_f16(a0, wA[c][0], z, 0, 0, 0);
                        z = __builtin_amdgcn_mfma_f32_16x16x32_f16(a1, wA[c][1], z, 0, 0, 0);
                        acc[c] = z;
                    }
                    float pi = sel4(acc[0], quad) + xp0;
                    float pf = sel4(acc[1], quad) + xp1;
                    float pg = sel4(acc[2], quad) + xp2;
                    float po = sel4(acc[3], quad) + xp3;
                    float iv = sig_p(pi),  fv = sig_p(pf);
                    float gv = tanh_p(pg), ov = sig_p(po);
                    cst = fmaf(fv, cst, iv * gv);
                    float th = tanh_p(cst * LOG2E2);
                    h1a[cur][quad * HSTR + col] = (_Float16)(ov * th); // h1[it]
                }
            } else {
                const bool doG = (it >= 2);             // gates for step it-2
                const bool doQ = (it >= 1 && it <= TT); // pI(it-1) for next iter

                // ds_reads first (both frag sets issue together)
                half8 a2, a3, b0, b1;
                if (doG) {
                    const _Float16* hb2 = h2a[prev] + (l16 & 3) * HSTR + quad * 8;
                    a2 = *(const half8*)hb2;
                    a3 = *(const half8*)(hb2 + 32);
                }
                if (doQ) {
                    const _Float16* hb1 = h1a[prev] + (l16 & 3) * HSTR + quad * 8;
                    b0 = *(const half8*)hb1;
                    b1 = *(const half8*)(hb1 + 32);
                }

                // read-window fill: pI(it-2) quad-selects (off the tail chain)
                float qp0, qp1, qp2, qp3;
                if (doG) {
                    qp0 = sel4(accQ[prev][0], quad);
                    qp1 = sel4(accQ[prev][1], quad);
                    qp2 = sel4(accQ[prev][2], quad);
                    qp3 = sel4(accQ[prev][3], quad);
                }

                // CRITICAL: gate MFMAs issue first (in-order MFMA pipe).
                f32x4 acc[4];
                if (doG) {
                    #pragma unroll
                    for (int c = 0; c < 4; ++c) {
                        f32x4 z = cbias[c];
                        z = __builtin_amdgcn_mfma_f32_16x16x32_f16(a2, wA[c][0], z, 0, 0, 0);
                        z = __builtin_amdgcn_mfma_f32_16x16x32_f16(a3, wA[c][1], z, 0, 0, 0);
                        acc[c] = z;
                    }
                }
                // pI(it-1) = Wih1 . h1[it-1] -> accQ[sub] (registers, consumed
                // NEXT iteration). Off-critical; issues behind gates, completes
                // under the VALU activation tail.
                if (doQ) {
                    #pragma unroll
                    for (int c = 0; c < 4; ++c) {
                        f32x4 z = Z;
                        z = __builtin_amdgcn_mfma_f32_16x16x32_f16(b0, wB[c][0], z, 0, 0, 0);
                        z = __builtin_amdgcn_mfma_f32_16x16x32_f16(b1, wB[c][1], z, 0, 0, 0);
                        accQ[sub][c] = z;
                    }
                }

                if (doG) {
                    // gates = Whh1.h2[it-3] + bias + pI(it-2) (hoisted qp)
                    float pi = sel4(acc[0], quad) + qp0;
                    float pf = sel4(acc[1], quad) + qp1;
                    float pg = sel4(acc[2], quad) + qp2;
                    float po = sel4(acc[3], quad) + qp3;
                    float iv = sig_p(pi),  fv = sig_p(pf);
                    float gv = tanh_p(pg), ov = sig_p(po);
                    cst = fmaf(fv, cst, iv * gv);
                    float hv = ov * tanh_p(cst * LOG2E2);
                    h2a[cur][quad * HSTR + col] = (_Float16)hv;            // h2[it-2]
                    if (it == TT + 1)
                        out[(size_t)(blockIdx.x * 4 + quad) * 64 + col] = hv;
                }
            }
            lds_barrier();   // LDS-only drain; x prefetch stays in flight
        }
    }
}

extern "C" void kernel_launch(void* const* d_in, const int* in_sizes, int n_in,
                              void* d_out, int out_size, void* d_ws, size_t ws_size,
                              hipStream_t stream) {
    const float* x    = (const float*)d_in[0];
    const float* Wih0 = (const float*)d_in[1];
    const float* Whh0 = (const float*)d_in[2];
    const float* bih0 = (const float*)d_in[3];
    const float* bhh0 = (const float*)d_in[4];
    const float* Wih1 = (const float*)d_in[5];
    const float* Whh1 = (const float*)d_in[6];
    const float* bih1 = (const float*)d_in[7];
    const float* bhh1 = (const float*)d_in[8];
    float* out = (float*)d_out;

    // 512 sequences / 4 per block = 128 blocks; 512 threads (8 waves, 2/SIMD).
    lstm2_fused<<<128, 512, 0, stream>>>(x, Wih0, Whh0, bih0, bhh0,
                                         Wih1, Whh1, bih1, bhh1, out);
}